// Round 1
// baseline (701.053 us; speedup 1.0000x reference)
//
#include <hip/hip_runtime.h>
#include <stdint.h>
#include <math.h>

// Problem constants
constexpr int T_ = 4;
constexpr int B_ = 8;
constexpr int C_ = 256;
constexpr int N_ = 256;          // H*W
constexpr int TN_ = 1024;        // T*N
constexpr int NH_ = 8;           // heads
constexpr int O3_ = 768;         // 3*C
constexpr int BIAS_ROWS_ = 6727; // 7*31*31

__device__ __forceinline__ float quant1f(float m) {
    // round(clip(m,0,1)) with round-half-to-even (matches jnp.round)
    return rintf(fminf(fmaxf(m, 0.0f), 1.0f));
}

// ---------------------------------------------------------------------------
// K1: qkv = BN(w_qkv @ xf)   out[b][o][l] (o in [0,768), l in [0,1024))
// X[b] is flat x reinterpreted as [C][TN] with row stride TN.
// 64x64 tile per block, 256 threads, 4x4 register tile, K-chunks of 16.
// ---------------------------------------------------------------------------
__global__ __launch_bounds__(256) void k1_qkv_gemm(
    const float* __restrict__ x, const float* __restrict__ w,
    const float* __restrict__ gamma, const float* __restrict__ beta,
    const float* __restrict__ mean, const float* __restrict__ var,
    float* __restrict__ out)
{
    __shared__ float Wt[16][65];   // [cc][oo]
    __shared__ float Xt[16][65];   // [cc][ll]
    const int b = blockIdx.z;
    const int oBase = blockIdx.y * 64;
    const int lBase = blockIdx.x * 64;
    const int tid = threadIdx.x;
    const int ty = tid >> 4, tx = tid & 15;
    const float* xb = x + (size_t)b * C_ * TN_;

    float acc[4][4];
#pragma unroll
    for (int i = 0; i < 4; ++i)
#pragma unroll
        for (int j = 0; j < 4; ++j) acc[i][j] = 0.0f;

    for (int kc = 0; kc < 16; ++kc) {
        // load W tile 64(o) x 16(c): coalesced over cc
        {
            const int cc = tid & 15, oo = tid >> 4;
#pragma unroll
            for (int r = 0; r < 4; ++r)
                Wt[cc][oo + 16 * r] = w[(size_t)(oBase + oo + 16 * r) * C_ + kc * 16 + cc];
        }
        // load X tile 16(c) x 64(l): coalesced over ll
        {
            const int ll = tid & 63, cc0 = tid >> 6;
#pragma unroll
            for (int r = 0; r < 4; ++r)
                Xt[cc0 + 4 * r][ll] = xb[(size_t)(kc * 16 + cc0 + 4 * r) * TN_ + lBase + ll];
        }
        __syncthreads();
#pragma unroll
        for (int cc = 0; cc < 16; ++cc) {
            float a[4], bx[4];
#pragma unroll
            for (int i = 0; i < 4; ++i) a[i] = Wt[cc][ty + 16 * i];
#pragma unroll
            for (int j = 0; j < 4; ++j) bx[j] = Xt[cc][tx + 16 * j];
#pragma unroll
            for (int i = 0; i < 4; ++i)
#pragma unroll
                for (int j = 0; j < 4; ++j) acc[i][j] += a[i] * bx[j];
        }
        __syncthreads();
    }

#pragma unroll
    for (int i = 0; i < 4; ++i) {
        const int o = oBase + ty + 16 * i;
        const float inv = 1.0f / sqrtf(var[o] + 1e-5f);
        const float g = gamma[o] * inv;
        const float mn = mean[o], bt = beta[o];
#pragma unroll
        for (int j = 0; j < 4; ++j) {
            const int l = lBase + tx + 16 * j;
            out[((size_t)b * O3_ + o) * TN_ + l] = (acc[i][j] - mn) * g + bt;
        }
    }
}

// ---------------------------------------------------------------------------
// K2: LIF over t on qkv_bn, pack 32 head-dims into one uint32 spike word.
// thread = (b, g, n) with g in [0,24): q heads 0-7, k heads 8-15, v 16-23.
// ---------------------------------------------------------------------------
__global__ __launch_bounds__(256) void k2_lif_pack(
    const float* __restrict__ qkv,
    uint32_t* __restrict__ qb, uint32_t* __restrict__ kb, uint32_t* __restrict__ vb)
{
    const int n = threadIdx.x;
    const int g = blockIdx.x;   // 0..23
    const int b = blockIdx.y;
    const int which = g >> 3, h = g & 7;
    uint32_t* dst = (which == 0) ? qb : (which == 1) ? kb : vb;
    const float* src = qkv + ((size_t)b * O3_ + g * 32) * TN_;

    float memv[32];
#pragma unroll
    for (int d = 0; d < 32; ++d) memv[d] = 0.0f;
    uint32_t prev = 0;

    for (int t = 0; t < T_; ++t) {
        uint32_t bits = 0;
#pragma unroll
        for (int d = 0; d < 32; ++d) {
            const float xv = src[(size_t)d * TN_ + t * N_ + n];
            const float m = (memv[d] - 0.5f * (float)((prev >> d) & 1u)) * 0.25f + xv;
            memv[d] = m;
            const float s = quant1f(m);
            bits |= ((uint32_t)s) << d;
        }
        prev = bits;
        dst[((size_t)b * NH_ + h) * TN_ + t * N_ + n] = bits;
    }
}

// ---------------------------------------------------------------------------
// K3: attention. Per (b,h): o[i,d] = 0.125 * sum_{j<(ti+1)*N} (popc(q_i&k_j)+bias) * v[j,d]
// bias[h,i,j] = bias_col[code(i)-code(j)+3363], code = 961t+31h+16... (31h + w)
// Block: one (b,h), 32 consecutive i (same time block -> uniform jmax).
// K,V spike words + code table + bias column staged in LDS.
// Output layout oatt[b][i][c=h*32+d] -> coalesced stores.
// ---------------------------------------------------------------------------
__global__ __launch_bounds__(256) void k3_attn(
    const uint32_t* __restrict__ qb, const uint32_t* __restrict__ kb,
    const uint32_t* __restrict__ vb, const float* __restrict__ bias_table,
    float* __restrict__ oatt)
{
    __shared__ float sb[BIAS_ROWS_ + 1];
    __shared__ uint32_t sk[TN_];
    __shared__ uint32_t sv[TN_];
    __shared__ unsigned short scode[TN_];

    const int tid = threadIdx.x;
    const int iBase = blockIdx.x * 32;
    const int h = blockIdx.y;
    const int b = blockIdx.z;

    for (int idx = tid; idx < BIAS_ROWS_; idx += 256)
        sb[idx] = bias_table[(size_t)idx * NH_ + h];

    const uint32_t* kbh = kb + ((size_t)b * NH_ + h) * TN_;
    const uint32_t* vbh = vb + ((size_t)b * NH_ + h) * TN_;
    for (int j = tid; j < TN_; j += 256) {
        sk[j] = kbh[j];
        sv[j] = vbh[j];
        const int tj = j >> 8, hj = (j >> 4) & 15, wj = j & 15;
        scode[j] = (unsigned short)(961 * tj + 31 * hj + wj);
    }
    __syncthreads();

    const int wv = tid >> 6;          // wave 0..3
    const int lane = tid & 63;
    const int half = lane >> 5;       // 0/1 -> two i per wave iteration
    const int d = lane & 31;

    const int ti = iBase >> 8;        // uniform across block
    const int jmax = (ti + 1) * N_;
    const uint32_t* qbh = qb + ((size_t)b * NH_ + h) * TN_;

    for (int s = 0; s < 4; ++s) {
        const int i = iBase + wv * 8 + s * 2 + half;
        const uint32_t q = qbh[i];
        const int hi = (i >> 4) & 15, wi = i & 15;
        const int ci = 961 * ti + 31 * hi + wi + 3363;
        float acc = 0.0f;
#pragma unroll 4
        for (int j = 0; j < jmax; ++j) {
            const uint32_t kk = sk[j];
            const uint32_t vv = sv[j];
            const float bvv = sb[ci - (int)scode[j]];
            const float a = (float)__popc(q & kk) + bvv;
            acc += ((vv >> d) & 1u) ? a : 0.0f;
        }
        oatt[((size_t)b * TN_ + i) * C_ + h * 32 + d] = 0.125f * acc;
    }
}

// ---------------------------------------------------------------------------
// K4: LIF over t on oatt [b][t*N+n][c] -> s2t same layout (float 0/1 spikes)
// thread = (b, n, c): all loads/stores coalesced over c.
// ---------------------------------------------------------------------------
__global__ __launch_bounds__(256) void k4_lif2(
    const float* __restrict__ oatt, float* __restrict__ s2t)
{
    const int c = threadIdx.x;
    const int n = blockIdx.x;   // 0..255
    const int b = blockIdx.y;
    float memv = 0.0f, spk = 0.0f;
    for (int t = 0; t < T_; ++t) {
        const size_t idx = ((size_t)b * TN_ + t * N_ + n) * C_ + c;
        const float m = (memv - 0.5f * spk) * 0.25f + oatt[idx];
        memv = m;
        const float s = quant1f(m);
        s2t[idx] = s;
        spk = s;
    }
}

// ---------------------------------------------------------------------------
// K5: proj GEMM + bias + BN.  pbn[b][o][l] = BN(sum_c wp[o][c]*s2t[b][l][c] + bp[o])
// s2t accessed as [l][c] (transposed GEMM B-operand).
// ---------------------------------------------------------------------------
__global__ __launch_bounds__(256) void k5_proj_gemm(
    const float* __restrict__ s2t, const float* __restrict__ w,
    const float* __restrict__ bp,
    const float* __restrict__ gamma, const float* __restrict__ beta,
    const float* __restrict__ mean, const float* __restrict__ var,
    float* __restrict__ pbn)
{
    __shared__ float Wt[16][65];   // [cc][oo]
    __shared__ float Xt[16][65];   // [cc][ll]
    const int b = blockIdx.z;
    const int oBase = blockIdx.y * 64;   // 4 tiles
    const int lBase = blockIdx.x * 64;   // 16 tiles
    const int tid = threadIdx.x;
    const int ty = tid >> 4, tx = tid & 15;
    const float* xb = s2t + (size_t)b * TN_ * C_;

    float acc[4][4];
#pragma unroll
    for (int i = 0; i < 4; ++i)
#pragma unroll
        for (int j = 0; j < 4; ++j) acc[i][j] = 0.0f;

    for (int kc = 0; kc < 16; ++kc) {
        {
            const int cc = tid & 15, oo = tid >> 4;
#pragma unroll
            for (int r = 0; r < 4; ++r)
                Wt[cc][oo + 16 * r] = w[(size_t)(oBase + oo + 16 * r) * C_ + kc * 16 + cc];
        }
        {
            const int cc = tid & 15, ll0 = tid >> 4;
#pragma unroll
            for (int r = 0; r < 4; ++r)
                Xt[cc][ll0 + 16 * r] = xb[(size_t)(lBase + ll0 + 16 * r) * C_ + kc * 16 + cc];
        }
        __syncthreads();
#pragma unroll
        for (int cc = 0; cc < 16; ++cc) {
            float a[4], bx[4];
#pragma unroll
            for (int i = 0; i < 4; ++i) a[i] = Wt[cc][ty + 16 * i];
#pragma unroll
            for (int j = 0; j < 4; ++j) bx[j] = Xt[cc][tx + 16 * j];
#pragma unroll
            for (int i = 0; i < 4; ++i)
#pragma unroll
                for (int j = 0; j < 4; ++j) acc[i][j] += a[i] * bx[j];
        }
        __syncthreads();
    }

#pragma unroll
    for (int i = 0; i < 4; ++i) {
        const int o = oBase + ty + 16 * i;
        const float inv = 1.0f / sqrtf(var[o] + 1e-5f);
        const float g = gamma[o] * inv;
        const float mn = mean[o], bt = beta[o], bpo = bp[o];
#pragma unroll
        for (int j = 0; j < 4; ++j) {
            const int l = lBase + tx + 16 * j;
            pbn[((size_t)b * C_ + o) * TN_ + l] = ((acc[i][j] + bpo) - mn) * g + bt;
        }
    }
}

// ---------------------------------------------------------------------------
// K6: final LIF over t, write output [T][B][C][N] (= [T,B,C,H,W])
// thread = (b, c, n): coalesced over n.
// ---------------------------------------------------------------------------
__global__ __launch_bounds__(256) void k6_lif3(
    const float* __restrict__ pbn, float* __restrict__ out)
{
    const int n = threadIdx.x;
    const int c = blockIdx.x;
    const int b = blockIdx.y;
    const float* src = pbn + ((size_t)b * C_ + c) * TN_;
    float memv = 0.0f, spk = 0.0f;
    for (int t = 0; t < T_; ++t) {
        const float m = (memv - 0.5f * spk) * 0.25f + src[t * N_ + n];
        memv = m;
        const float s = quant1f(m);
        out[(((size_t)t * B_ + b) * C_ + c) * N_ + n] = s;
        spk = s;
    }
}

// ---------------------------------------------------------------------------
extern "C" void kernel_launch(void* const* d_in, const int* in_sizes, int n_in,
                              void* d_out, int out_size, void* d_ws, size_t ws_size,
                              hipStream_t stream)
{
    const float* x          = (const float*)d_in[0];
    const float* w_qkv      = (const float*)d_in[1];
    const float* qkv_gamma  = (const float*)d_in[2];
    const float* qkv_beta   = (const float*)d_in[3];
    const float* qkv_mean   = (const float*)d_in[4];
    const float* qkv_var    = (const float*)d_in[5];
    const float* bias_table = (const float*)d_in[6];
    const float* w_proj     = (const float*)d_in[7];
    const float* b_proj     = (const float*)d_in[8];
    const float* proj_gamma = (const float*)d_in[9];
    const float* proj_beta  = (const float*)d_in[10];
    const float* proj_mean  = (const float*)d_in[11];
    const float* proj_var   = (const float*)d_in[12];
    float* out = (float*)d_out;

    // workspace layout (bytes)
    char* ws = (char*)d_ws;
    float*    qkv_bn = (float*)(ws + 0);                      // 8*768*1024 f32 = 25165824 B
    float*    oatt   = (float*)(ws + 25165824);               // 8*1024*256 f32 =  8388608 B
    float*    s2t    = (float*)(ws + 33554432);               // 8*1024*256 f32 =  8388608 B
    float*    pbn    = (float*)(ws + 41943040);               // 8*256*1024 f32 =  8388608 B
    uint32_t* qbits  = (uint32_t*)(ws + 50331648);            // 8*8*1024 u32 = 262144 B
    uint32_t* kbits  = (uint32_t*)(ws + 50593792);
    uint32_t* vbits  = (uint32_t*)(ws + 50855936);            // end = 51118080 B

    k1_qkv_gemm<<<dim3(16, 12, 8), 256, 0, stream>>>(
        x, w_qkv, qkv_gamma, qkv_beta, qkv_mean, qkv_var, qkv_bn);

    k2_lif_pack<<<dim3(24, 8), 256, 0, stream>>>(qkv_bn, qbits, kbits, vbits);

    k3_attn<<<dim3(32, 8, 8), 256, 0, stream>>>(qbits, kbits, vbits, bias_table, oatt);

    k4_lif2<<<dim3(256, 8), 256, 0, stream>>>(oatt, s2t);

    k5_proj_gemm<<<dim3(16, 4, 8), 256, 0, stream>>>(
        s2t, w_proj, b_proj, proj_gamma, proj_beta, proj_mean, proj_var, pbn);

    k6_lif3<<<dim3(256, 8), 256, 0, stream>>>(pbn, out);
}

// Round 2
// 383.080 us; speedup vs baseline: 1.8300x; 1.8300x over previous
//
#include <hip/hip_runtime.h>
#include <stdint.h>
#include <math.h>

// Problem constants
constexpr int T_ = 4;
constexpr int B_ = 8;
constexpr int C_ = 256;
constexpr int N_ = 256;          // H*W
constexpr int TN_ = 1024;        // T*N
constexpr int NH_ = 8;           // heads
constexpr int O3_ = 768;         // 3*C
constexpr int BIAS_ROWS_ = 6727; // 7*31*31

__device__ __forceinline__ float quant1f(float m) {
    return rintf(fminf(fmaxf(m, 0.0f), 1.0f));
}

// ---------------------------------------------------------------------------
// K1: qkv = BN(w_qkv @ xf)   out[b][o][l]
// ---------------------------------------------------------------------------
__global__ __launch_bounds__(256) void k1_qkv_gemm(
    const float* __restrict__ x, const float* __restrict__ w,
    const float* __restrict__ gamma, const float* __restrict__ beta,
    const float* __restrict__ mean, const float* __restrict__ var,
    float* __restrict__ out)
{
    __shared__ float Wt[16][65];
    __shared__ float Xt[16][65];
    const int b = blockIdx.z;
    const int oBase = blockIdx.y * 64;
    const int lBase = blockIdx.x * 64;
    const int tid = threadIdx.x;
    const int ty = tid >> 4, tx = tid & 15;
    const float* xb = x + (size_t)b * C_ * TN_;

    float acc[4][4];
#pragma unroll
    for (int i = 0; i < 4; ++i)
#pragma unroll
        for (int j = 0; j < 4; ++j) acc[i][j] = 0.0f;

    for (int kc = 0; kc < 16; ++kc) {
        {
            const int cc = tid & 15, oo = tid >> 4;
#pragma unroll
            for (int r = 0; r < 4; ++r)
                Wt[cc][oo + 16 * r] = w[(size_t)(oBase + oo + 16 * r) * C_ + kc * 16 + cc];
        }
        {
            const int ll = tid & 63, cc0 = tid >> 6;
#pragma unroll
            for (int r = 0; r < 4; ++r)
                Xt[cc0 + 4 * r][ll] = xb[(size_t)(kc * 16 + cc0 + 4 * r) * TN_ + lBase + ll];
        }
        __syncthreads();
#pragma unroll
        for (int cc = 0; cc < 16; ++cc) {
            float a[4], bx[4];
#pragma unroll
            for (int i = 0; i < 4; ++i) a[i] = Wt[cc][ty + 16 * i];
#pragma unroll
            for (int j = 0; j < 4; ++j) bx[j] = Xt[cc][tx + 16 * j];
#pragma unroll
            for (int i = 0; i < 4; ++i)
#pragma unroll
                for (int j = 0; j < 4; ++j) acc[i][j] += a[i] * bx[j];
        }
        __syncthreads();
    }

#pragma unroll
    for (int i = 0; i < 4; ++i) {
        const int o = oBase + ty + 16 * i;
        const float inv = 1.0f / sqrtf(var[o] + 1e-5f);
        const float g = gamma[o] * inv;
        const float mn = mean[o], bt = beta[o];
#pragma unroll
        for (int j = 0; j < 4; ++j) {
            const int l = lBase + tx + 16 * j;
            out[((size_t)b * O3_ + o) * TN_ + l] = (acc[i][j] - mn) * g + bt;
        }
    }
}

// ---------------------------------------------------------------------------
// K2: LIF over t on qkv_bn, pack 32 head-dims into one uint32 spike word.
// ---------------------------------------------------------------------------
__global__ __launch_bounds__(256) void k2_lif_pack(
    const float* __restrict__ qkv,
    uint32_t* __restrict__ qb, uint32_t* __restrict__ kb, uint32_t* __restrict__ vb)
{
    const int n = threadIdx.x;
    const int g = blockIdx.x;
    const int b = blockIdx.y;
    const int which = g >> 3, h = g & 7;
    uint32_t* dst = (which == 0) ? qb : (which == 1) ? kb : vb;
    const float* src = qkv + ((size_t)b * O3_ + g * 32) * TN_;

    float memv[32];
#pragma unroll
    for (int d = 0; d < 32; ++d) memv[d] = 0.0f;
    uint32_t prev = 0;

    for (int t = 0; t < T_; ++t) {
        uint32_t bits = 0;
#pragma unroll
        for (int d = 0; d < 32; ++d) {
            const float xv = src[(size_t)d * TN_ + t * N_ + n];
            const float m = (memv[d] - 0.5f * (float)((prev >> d) & 1u)) * 0.25f + xv;
            memv[d] = m;
            const float s = quant1f(m);
            bits |= ((uint32_t)s) << d;
        }
        prev = bits;
        dst[((size_t)b * NH_ + h) * TN_ + t * N_ + n] = bits;
    }
}

// ---------------------------------------------------------------------------
// K3v: expand v spike bits to fp32 Vf[h][j][b*32+d]  (GEMM B operand)
// ---------------------------------------------------------------------------
__global__ __launch_bounds__(256) void k3_vexpand(
    const uint32_t* __restrict__ vb, float* __restrict__ Vf)
{
    const int j = blockIdx.x;
    const int h = blockIdx.y;
    const int tid = threadIdx.x;      // = b*32 + d
    const int b = tid >> 5, d = tid & 31;
    const uint32_t w = vb[((size_t)b * NH_ + h) * TN_ + j];
    Vf[((size_t)h * TN_ + j) * 256 + tid] = (float)((w >> d) & 1u);
}

// ---------------------------------------------------------------------------
// K3t: ballot bit-transpose of k and v spikes into per-(b,h,t) column masks.
// ksel[((bh*4+t)*32+d)*4+q] = 64-bit mask over j in quarter q of time block t.
// ---------------------------------------------------------------------------
__global__ __launch_bounds__(256) void k3_transpose(
    const uint32_t* __restrict__ kb, const uint32_t* __restrict__ vb,
    uint64_t* __restrict__ ksel, uint64_t* __restrict__ vsel)
{
    const int t = blockIdx.x;
    const int h = blockIdx.y;
    const int b = blockIdx.z;
    const int bh = b * NH_ + h;
    const int tid = threadIdx.x;
    const int q = tid >> 6, lane = tid & 63;
    const int j = t * N_ + q * 64 + lane;

    const uint32_t kw = kb[(size_t)bh * TN_ + j];
    const uint32_t vw = vb[(size_t)bh * TN_ + j];
#pragma unroll
    for (int d = 0; d < 32; ++d) {
        const uint64_t mk = __ballot((kw >> d) & 1u);
        const uint64_t mv = __ballot((vw >> d) & 1u);
        if (lane == 0) {
            ksel[((size_t)(bh * 4 + t) * 32 + d) * 4 + q] = mk;
            vsel[((size_t)(bh * 4 + t) * 32 + d) * 4 + q] = mv;
        }
    }
}

// ---------------------------------------------------------------------------
// K3g: G_t[d2][d] = sum_{j < (t+1)*256} k[j,d2]*v[j,d]  (cumulative over t)
// ---------------------------------------------------------------------------
__global__ __launch_bounds__(256) void k3_gram(
    const uint64_t* __restrict__ ksel, const uint64_t* __restrict__ vsel,
    float* __restrict__ Gf)
{
    const int bh = blockIdx.x;
    const int tid = threadIdx.x;
    const int d = tid & 31;
#pragma unroll
    for (int s = 0; s < 4; ++s) {
        const int d2 = (tid >> 5) + 8 * s;
        int cum = 0;
#pragma unroll
        for (int t = 0; t < T_; ++t) {
            const uint64_t* kp = ksel + ((size_t)(bh * 4 + t) * 32 + d2) * 4;
            const uint64_t* vp = vsel + ((size_t)(bh * 4 + t) * 32 + d) * 4;
            int p = 0;
#pragma unroll
            for (int w = 0; w < 4; ++w) p += __popcll(kp[w] & vp[w]);
            cum += p;
            Gf[(size_t)(bh * 4 + t) * 1024 + d2 * 32 + d] = (float)cum;
        }
    }
}

// ---------------------------------------------------------------------------
// K3s1: S1[i,d] = sum_{d2} qbit[i,d2] * G_ti[d2,d]  -> oatt (unscaled)
// ---------------------------------------------------------------------------
__global__ __launch_bounds__(256) void k3_s1(
    const uint32_t* __restrict__ qb, const float* __restrict__ Gf,
    float* __restrict__ oatt)
{
    __shared__ float sG[1024];
    const int ti = blockIdx.x;
    const int h = blockIdx.y;
    const int b = blockIdx.z;
    const int bh = b * NH_ + h;
    const int tid = threadIdx.x;
    const int d = tid & 31;

    for (int idx = tid; idx < 1024; idx += 256)
        sG[idx] = Gf[(size_t)(bh * 4 + ti) * 1024 + idx];
    __syncthreads();

    const uint32_t* qbh = qb + (size_t)bh * TN_;
    for (int step = 0; step < 32; ++step) {
        const int i = ti * N_ + step * 8 + (tid >> 5);
        const uint32_t q = qbh[i];
        float acc = 0.0f;
#pragma unroll
        for (int d2 = 0; d2 < 32; ++d2)
            acc += ((q >> d2) & 1u) ? sG[d2 * 32 + d] : 0.0f;
        oatt[((size_t)b * TN_ + i) * C_ + h * 32 + d] = acc;
    }
}

// ---------------------------------------------------------------------------
// K3gemm: S2 = biasM @ Vf per (h, ti);  oatt = 0.125*(S1 + S2)
// A[i][j] = biascol_h[ci - cj] gathered from LDS-staged column.
// ---------------------------------------------------------------------------
__global__ __launch_bounds__(256) void k3_bias_gemm(
    const float* __restrict__ Vf, const float* __restrict__ bias_table,
    float* __restrict__ oatt)
{
    __shared__ float sb[BIAS_ROWS_ + 1];
    __shared__ float At[16][65];
    __shared__ float Bt[16][65];
    const int z = blockIdx.z;
    const int h = z >> 2;
    const int ti = 3 - (z & 3);          // heavy time-blocks dispatched first
    const int iTile = blockIdx.y;        // 0..3 (64 i each within the 256-i block)
    const int nBase = blockIdx.x * 64;   // 0..3 over 256 (b*32+d)
    const int tid = threadIdx.x;

    for (int idx = tid; idx < BIAS_ROWS_; idx += 256)
        sb[idx] = bias_table[(size_t)idx * NH_ + h];
    __syncthreads();

    const int ty = tid >> 4, tx = tid & 15;
    float acc[4][4];
#pragma unroll
    for (int i = 0; i < 4; ++i)
#pragma unroll
        for (int j = 0; j < 4; ++j) acc[i][j] = 0.0f;

    // A-loader thread mapping: cc = tid&15 (j within chunk), ii = (tid>>4) + 16r
    const int a_cc = tid & 15, a_ii0 = tid >> 4;
    int ciRow[4];
#pragma unroll
    for (int r = 0; r < 4; ++r) {
        const int i = ti * N_ + iTile * 64 + a_ii0 + 16 * r;
        ciRow[r] = 3363 + 961 * ti + 31 * ((i >> 4) & 15) + (i & 15);
    }

    const int kcMax = (ti + 1) * 16;
    for (int kc = 0; kc < kcMax; ++kc) {
        {
            const int tj = kc >> 4, hj = kc & 15;
            const int cj = 961 * tj + 31 * hj + a_cc;
#pragma unroll
            for (int r = 0; r < 4; ++r)
                At[a_cc][a_ii0 + 16 * r] = sb[ciRow[r] - cj];
        }
        {
            const int ll = tid & 63, cc0 = tid >> 6;
#pragma unroll
            for (int r = 0; r < 4; ++r)
                Bt[cc0 + 4 * r][ll] = Vf[((size_t)h * TN_ + kc * 16 + cc0 + 4 * r) * 256 + nBase + ll];
        }
        __syncthreads();
#pragma unroll
        for (int cc = 0; cc < 16; ++cc) {
            float a[4], bx[4];
#pragma unroll
            for (int i = 0; i < 4; ++i) a[i] = At[cc][ty + 16 * i];
#pragma unroll
            for (int j = 0; j < 4; ++j) bx[j] = Bt[cc][tx + 16 * j];
#pragma unroll
            for (int i = 0; i < 4; ++i)
#pragma unroll
                for (int j = 0; j < 4; ++j) acc[i][j] += a[i] * bx[j];
        }
        __syncthreads();
    }

#pragma unroll
    for (int i = 0; i < 4; ++i) {
        const int ig = ti * N_ + iTile * 64 + ty + 16 * i;
#pragma unroll
        for (int j = 0; j < 4; ++j) {
            const int n = nBase + tx + 16 * j;
            const int b = n >> 5, d = n & 31;
            const size_t idx = ((size_t)b * TN_ + ig) * C_ + h * 32 + d;
            oatt[idx] = 0.125f * (acc[i][j] + oatt[idx]);
        }
    }
}

// ---------------------------------------------------------------------------
// K4: LIF over t on oatt [b][t*N+n][c] -> s2t
// ---------------------------------------------------------------------------
__global__ __launch_bounds__(256) void k4_lif2(
    const float* __restrict__ oatt, float* __restrict__ s2t)
{
    const int c = threadIdx.x;
    const int n = blockIdx.x;
    const int b = blockIdx.y;
    float memv = 0.0f, spk = 0.0f;
    for (int t = 0; t < T_; ++t) {
        const size_t idx = ((size_t)b * TN_ + t * N_ + n) * C_ + c;
        const float m = (memv - 0.5f * spk) * 0.25f + oatt[idx];
        memv = m;
        const float s = quant1f(m);
        s2t[idx] = s;
        spk = s;
    }
}

// ---------------------------------------------------------------------------
// K5: proj GEMM + bias + BN.
// ---------------------------------------------------------------------------
__global__ __launch_bounds__(256) void k5_proj_gemm(
    const float* __restrict__ s2t, const float* __restrict__ w,
    const float* __restrict__ bp,
    const float* __restrict__ gamma, const float* __restrict__ beta,
    const float* __restrict__ mean, const float* __restrict__ var,
    float* __restrict__ pbn)
{
    __shared__ float Wt[16][65];
    __shared__ float Xt[16][65];
    const int b = blockIdx.z;
    const int oBase = blockIdx.y * 64;
    const int lBase = blockIdx.x * 64;
    const int tid = threadIdx.x;
    const int ty = tid >> 4, tx = tid & 15;
    const float* xb = s2t + (size_t)b * TN_ * C_;

    float acc[4][4];
#pragma unroll
    for (int i = 0; i < 4; ++i)
#pragma unroll
        for (int j = 0; j < 4; ++j) acc[i][j] = 0.0f;

    for (int kc = 0; kc < 16; ++kc) {
        {
            const int cc = tid & 15, oo = tid >> 4;
#pragma unroll
            for (int r = 0; r < 4; ++r)
                Wt[cc][oo + 16 * r] = w[(size_t)(oBase + oo + 16 * r) * C_ + kc * 16 + cc];
        }
        {
            const int cc = tid & 15, ll0 = tid >> 4;
#pragma unroll
            for (int r = 0; r < 4; ++r)
                Xt[cc][ll0 + 16 * r] = xb[(size_t)(lBase + ll0 + 16 * r) * C_ + kc * 16 + cc];
        }
        __syncthreads();
#pragma unroll
        for (int cc = 0; cc < 16; ++cc) {
            float a[4], bx[4];
#pragma unroll
            for (int i = 0; i < 4; ++i) a[i] = Wt[cc][ty + 16 * i];
#pragma unroll
            for (int j = 0; j < 4; ++j) bx[j] = Xt[cc][tx + 16 * j];
#pragma unroll
            for (int i = 0; i < 4; ++i)
#pragma unroll
                for (int j = 0; j < 4; ++j) acc[i][j] += a[i] * bx[j];
        }
        __syncthreads();
    }

#pragma unroll
    for (int i = 0; i < 4; ++i) {
        const int o = oBase + ty + 16 * i;
        const float inv = 1.0f / sqrtf(var[o] + 1e-5f);
        const float g = gamma[o] * inv;
        const float mn = mean[o], bt = beta[o], bpo = bp[o];
#pragma unroll
        for (int j = 0; j < 4; ++j) {
            const int l = lBase + tx + 16 * j;
            pbn[((size_t)b * C_ + o) * TN_ + l] = ((acc[i][j] + bpo) - mn) * g + bt;
        }
    }
}

// ---------------------------------------------------------------------------
// K6: final LIF over t, write output [T][B][C][N]
// ---------------------------------------------------------------------------
__global__ __launch_bounds__(256) void k6_lif3(
    const float* __restrict__ pbn, float* __restrict__ out)
{
    const int n = threadIdx.x;
    const int c = blockIdx.x;
    const int b = blockIdx.y;
    const float* src = pbn + ((size_t)b * C_ + c) * TN_;
    float memv = 0.0f, spk = 0.0f;
    for (int t = 0; t < T_; ++t) {
        const float m = (memv - 0.5f * spk) * 0.25f + src[t * N_ + n];
        memv = m;
        const float s = quant1f(m);
        out[(((size_t)t * B_ + b) * C_ + c) * N_ + n] = s;
        spk = s;
    }
}

// ---------------------------------------------------------------------------
extern "C" void kernel_launch(void* const* d_in, const int* in_sizes, int n_in,
                              void* d_out, int out_size, void* d_ws, size_t ws_size,
                              hipStream_t stream)
{
    const float* x          = (const float*)d_in[0];
    const float* w_qkv      = (const float*)d_in[1];
    const float* qkv_gamma  = (const float*)d_in[2];
    const float* qkv_beta   = (const float*)d_in[3];
    const float* qkv_mean   = (const float*)d_in[4];
    const float* qkv_var    = (const float*)d_in[5];
    const float* bias_table = (const float*)d_in[6];
    const float* w_proj     = (const float*)d_in[7];
    const float* b_proj     = (const float*)d_in[8];
    const float* proj_gamma = (const float*)d_in[9];
    const float* proj_beta  = (const float*)d_in[10];
    const float* proj_mean  = (const float*)d_in[11];
    const float* proj_var   = (const float*)d_in[12];
    float* out = (float*)d_out;

    // workspace layout (bytes)
    char* ws = (char*)d_ws;
    float*    qkv_bn = (float*)(ws + 0);            // 25165824 B (dead after K2)
    //   overlays inside the qkv_bn region (used only after K2 completes):
    float*    Vf     = (float*)(ws + 0);            //  8388608 B
    uint64_t* ksel   = (uint64_t*)(ws + 8388608);   //   262144 B
    uint64_t* vsel   = (uint64_t*)(ws + 8650752);   //   262144 B
    float*    Gf     = (float*)(ws + 8912896);      //   262144 B (ends 9175040)
    float*    oatt   = (float*)(ws + 25165824);     //  8388608 B
    float*    s2t    = (float*)(ws + 33554432);     //  8388608 B
    float*    pbn    = (float*)(ws + 41943040);     //  8388608 B
    uint32_t* qbits  = (uint32_t*)(ws + 50331648);  //   262144 B
    uint32_t* kbits  = (uint32_t*)(ws + 50593792);
    uint32_t* vbits  = (uint32_t*)(ws + 50855936);  // end 51118080

    k1_qkv_gemm<<<dim3(16, 12, 8), 256, 0, stream>>>(
        x, w_qkv, qkv_gamma, qkv_beta, qkv_mean, qkv_var, qkv_bn);

    k2_lif_pack<<<dim3(24, 8), 256, 0, stream>>>(qkv_bn, qbits, kbits, vbits);

    k3_vexpand<<<dim3(TN_, NH_), 256, 0, stream>>>(vbits, Vf);

    k3_transpose<<<dim3(4, 8, 8), 256, 0, stream>>>(kbits, vbits, ksel, vsel);

    k3_gram<<<dim3(64), 256, 0, stream>>>(ksel, vsel, Gf);

    k3_s1<<<dim3(4, 8, 8), 256, 0, stream>>>(qbits, Gf, oatt);

    k3_bias_gemm<<<dim3(4, 4, 32), 256, 0, stream>>>(Vf, bias_table, oatt);

    k4_lif2<<<dim3(256, 8), 256, 0, stream>>>(oatt, s2t);

    k5_proj_gemm<<<dim3(16, 4, 8), 256, 0, stream>>>(
        s2t, w_proj, b_proj, proj_gamma, proj_beta, proj_mean, proj_var, pbn);

    k6_lif3<<<dim3(256, 8), 256, 0, stream>>>(pbn, out);
}

// Round 3
// 271.905 us; speedup vs baseline: 2.5783x; 1.4089x over previous
//
#include <hip/hip_runtime.h>
#include <stdint.h>
#include <math.h>

// Problem constants
constexpr int T_ = 4;
constexpr int B_ = 8;
constexpr int C_ = 256;
constexpr int N_ = 256;          // H*W
constexpr int TN_ = 1024;        // T*N
constexpr int NH_ = 8;           // heads
constexpr int O3_ = 768;         // 3*C
constexpr int BIAS_ROWS_ = 6727; // 7*31*31
constexpr int BCOL_P_ = 6784;    // padded per-head bias column

__device__ __constant__ int TI_OF[10] = {0,1,1,2,2,2,3,3,3,3};
__device__ __constant__ int TJ_OF[10] = {0,0,1,0,1,2,0,1,2,3};

__device__ __forceinline__ float quant1f(float m) {
    return rintf(fminf(fmaxf(m, 0.0f), 1.0f));
}

// ---------------------------------------------------------------------------
// K0: compact bias_table column per head: bcol[h][r] = bias_table[r*8+h]
// ---------------------------------------------------------------------------
__global__ __launch_bounds__(256) void k0_bcol(
    const float* __restrict__ bias_table, float* __restrict__ bcol)
{
    const int idx = blockIdx.x * 256 + threadIdx.x;
    if (idx >= NH_ * BCOL_P_) return;
    const int h = idx / BCOL_P_, r = idx % BCOL_P_;
    bcol[idx] = (r < BIAS_ROWS_) ? bias_table[(size_t)r * NH_ + h] : 0.0f;
}

// ---------------------------------------------------------------------------
// K1: qkv = BN(w_qkv @ xf)   out[b][o][l]
// ---------------------------------------------------------------------------
__global__ __launch_bounds__(256) void k1_qkv_gemm(
    const float* __restrict__ x, const float* __restrict__ w,
    const float* __restrict__ gamma, const float* __restrict__ beta,
    const float* __restrict__ mean, const float* __restrict__ var,
    float* __restrict__ out)
{
    __shared__ float Wt[16][65];
    __shared__ float Xt[16][65];
    const int b = blockIdx.z;
    const int oBase = blockIdx.y * 64;
    const int lBase = blockIdx.x * 64;
    const int tid = threadIdx.x;
    const int ty = tid >> 4, tx = tid & 15;
    const float* xb = x + (size_t)b * C_ * TN_;

    float acc[4][4];
#pragma unroll
    for (int i = 0; i < 4; ++i)
#pragma unroll
        for (int j = 0; j < 4; ++j) acc[i][j] = 0.0f;

    for (int kc = 0; kc < 16; ++kc) {
        {
            const int cc = tid & 15, oo = tid >> 4;
#pragma unroll
            for (int r = 0; r < 4; ++r)
                Wt[cc][oo + 16 * r] = w[(size_t)(oBase + oo + 16 * r) * C_ + kc * 16 + cc];
        }
        {
            const int ll = tid & 63, cc0 = tid >> 6;
#pragma unroll
            for (int r = 0; r < 4; ++r)
                Xt[cc0 + 4 * r][ll] = xb[(size_t)(kc * 16 + cc0 + 4 * r) * TN_ + lBase + ll];
        }
        __syncthreads();
#pragma unroll
        for (int cc = 0; cc < 16; ++cc) {
            float a[4], bx[4];
#pragma unroll
            for (int i = 0; i < 4; ++i) a[i] = Wt[cc][ty + 16 * i];
#pragma unroll
            for (int j = 0; j < 4; ++j) bx[j] = Xt[cc][tx + 16 * j];
#pragma unroll
            for (int i = 0; i < 4; ++i)
#pragma unroll
                for (int j = 0; j < 4; ++j) acc[i][j] += a[i] * bx[j];
        }
        __syncthreads();
    }

#pragma unroll
    for (int i = 0; i < 4; ++i) {
        const int o = oBase + ty + 16 * i;
        const float inv = 1.0f / sqrtf(var[o] + 1e-5f);
        const float g = gamma[o] * inv;
        const float mn = mean[o], bt = beta[o];
#pragma unroll
        for (int j = 0; j < 4; ++j) {
            const int l = lBase + tx + 16 * j;
            out[((size_t)b * O3_ + o) * TN_ + l] = (acc[i][j] - mn) * g + bt;
        }
    }
}

// ---------------------------------------------------------------------------
// K2: LIF over t on qkv_bn, pack 32 head-dims into one uint32 spike word.
// ---------------------------------------------------------------------------
__global__ __launch_bounds__(256) void k2_lif_pack(
    const float* __restrict__ qkv,
    uint32_t* __restrict__ qb, uint32_t* __restrict__ kb, uint32_t* __restrict__ vb)
{
    const int n = threadIdx.x;
    const int g = blockIdx.x;
    const int b = blockIdx.y;
    const int which = g >> 3, h = g & 7;
    uint32_t* dst = (which == 0) ? qb : (which == 1) ? kb : vb;
    const float* src = qkv + ((size_t)b * O3_ + g * 32) * TN_;

    float memv[32];
#pragma unroll
    for (int d = 0; d < 32; ++d) memv[d] = 0.0f;
    uint32_t prev = 0;

    for (int t = 0; t < T_; ++t) {
        uint32_t bits = 0;
#pragma unroll
        for (int d = 0; d < 32; ++d) {
            const float xv = src[(size_t)d * TN_ + t * N_ + n];
            const float m = (memv[d] - 0.5f * (float)((prev >> d) & 1u)) * 0.25f + xv;
            memv[d] = m;
            const float s = quant1f(m);
            bits |= ((uint32_t)s) << d;
        }
        prev = bits;
        dst[((size_t)b * NH_ + h) * TN_ + t * N_ + n] = bits;
    }
}

// ---------------------------------------------------------------------------
// K3t: ballot bit-transpose of k and v spikes into per-(b,h,t) column masks.
// ---------------------------------------------------------------------------
__global__ __launch_bounds__(256) void k3_transpose(
    const uint32_t* __restrict__ kb, const uint32_t* __restrict__ vb,
    uint64_t* __restrict__ ksel, uint64_t* __restrict__ vsel)
{
    const int t = blockIdx.x;
    const int h = blockIdx.y;
    const int b = blockIdx.z;
    const int bh = b * NH_ + h;
    const int tid = threadIdx.x;
    const int q = tid >> 6, lane = tid & 63;
    const int j = t * N_ + q * 64 + lane;

    const uint32_t kw = kb[(size_t)bh * TN_ + j];
    const uint32_t vw = vb[(size_t)bh * TN_ + j];
#pragma unroll
    for (int d = 0; d < 32; ++d) {
        const uint64_t mk = __ballot((kw >> d) & 1u);
        const uint64_t mv = __ballot((vw >> d) & 1u);
        if (lane == 0) {
            ksel[((size_t)(bh * 4 + t) * 32 + d) * 4 + q] = mk;
            vsel[((size_t)(bh * 4 + t) * 32 + d) * 4 + q] = mv;
        }
    }
}

// ---------------------------------------------------------------------------
// K3g: G_t[d2][d] = sum_{j < (t+1)*256} k[j,d2]*v[j,d]  (cumulative over t)
// ---------------------------------------------------------------------------
__global__ __launch_bounds__(256) void k3_gram(
    const uint64_t* __restrict__ ksel, const uint64_t* __restrict__ vsel,
    float* __restrict__ Gf)
{
    const int bh = blockIdx.x;
    const int tid = threadIdx.x;
    const int d = tid & 31;
#pragma unroll
    for (int s = 0; s < 4; ++s) {
        const int d2 = (tid >> 5) + 8 * s;
        int cum = 0;
#pragma unroll
        for (int t = 0; t < T_; ++t) {
            const uint64_t* kp = ksel + ((size_t)(bh * 4 + t) * 32 + d2) * 4;
            const uint64_t* vp = vsel + ((size_t)(bh * 4 + t) * 32 + d) * 4;
            int p = 0;
#pragma unroll
            for (int w = 0; w < 4; ++w) p += __popcll(kp[w] & vp[w]);
            cum += p;
            Gf[(size_t)(bh * 4 + t) * 1024 + d2 * 32 + d] = (float)cum;
        }
    }
}

// ---------------------------------------------------------------------------
// K3s1: S1[i,d] = sum_{d2} qbit[i,d2] * G_ti[d2,d]  -> oatt (unscaled)
// ---------------------------------------------------------------------------
__global__ __launch_bounds__(256) void k3_s1(
    const uint32_t* __restrict__ qb, const float* __restrict__ Gf,
    float* __restrict__ oatt)
{
    __shared__ float sG[1024];
    const int ti = blockIdx.x;
    const int h = blockIdx.y;
    const int b = blockIdx.z;
    const int bh = b * NH_ + h;
    const int tid = threadIdx.x;
    const int d = tid & 31;

    for (int idx = tid; idx < 1024; idx += 256)
        sG[idx] = Gf[(size_t)(bh * 4 + ti) * 1024 + idx];
    __syncthreads();

    const uint32_t* qbh = qb + (size_t)bh * TN_;
    for (int step = 0; step < 32; ++step) {
        const int i = ti * N_ + step * 8 + (tid >> 5);
        const uint32_t q = qbh[i];
        float acc = 0.0f;
#pragma unroll
        for (int d2 = 0; d2 < 32; ++d2)
            acc += ((q >> d2) & 1u) ? sG[d2 * 32 + d] : 0.0f;
        oatt[((size_t)b * TN_ + i) * C_ + h * 32 + d] = acc;
    }
}

// ---------------------------------------------------------------------------
// K3gemm: balanced split-K bias GEMM.
// Block = (h, (ti,tj) pair, iTile(64 rows), nTile(64 cols)); K = 256 (one tj).
// For j = tj*256 + kc*16 + cc: hj=kc, wj=cc -> A bias values consecutive in cc
// within a 640-float window of bcol. B-tile expanded from v spike bits.
// Writes partial plane tj (packed rows i >= tj*256, layout [b][rowL][c]).
// ---------------------------------------------------------------------------
__global__ __launch_bounds__(256) void k3_bias_gemm(
    const uint32_t* __restrict__ vb, const float* __restrict__ bcol,
    float* __restrict__ p0, float* __restrict__ p1,
    float* __restrict__ p2, float* __restrict__ p3)
{
    __shared__ float sbl[640];
    __shared__ float Bt[16][64];

    const int z = blockIdx.z;            // 0..79
    const int h = z / 10;
    const int p = z % 10;
    const int ti = TI_OF[p], tj = TJ_OF[p];
    const int dt = ti - tj;
    const int iTile = blockIdx.y;        // 0..3
    const int nBase = blockIdx.x * 64;   // 0..3
    const int tid = threadIdx.x;

    // stage bias window: indices used are base..base+639 (in [0, 6784))
    const int base = 3363 + 961 * dt + 124 * iTile - 480;
    const float* bch = bcol + h * BCOL_P_;
    for (int s = tid; s < 640; s += 256) sbl[s] = bch[base + s];

    const int ty = tid >> 4, tx = tid & 15;
    const int ii0 = ty * 4;                          // 4 consecutive rows
    const int hi = (iTile * 64 + ii0) >> 4;          // same for all 4 rows
    const int wi0 = ii0 & 15;
    const int L0 = 31 * hi + wi0 - 124 * iTile + 480; // window-local A base (r=0)

    // Bt staging indices (per kc)
    const int ccb = tid >> 4;
    const int nb = nBase + (tid & 15) * 4;
    const int d0 = nb & 31;
    const uint32_t* vbw = vb + (((size_t)(nb >> 5)) * NH_ + h) * TN_ + tj * 256 + ccb;

    float acc[4][4];
#pragma unroll
    for (int i = 0; i < 4; ++i)
#pragma unroll
        for (int j = 0; j < 4; ++j) acc[i][j] = 0.0f;

    __syncthreads();  // sbl ready

    for (int kc = 0; kc < 16; ++kc) {
        {
            const uint32_t w = vbw[kc * 16];
            float4 bv;
            bv.x = (float)((w >> d0) & 1u);
            bv.y = (float)((w >> (d0 + 1)) & 1u);
            bv.z = (float)((w >> (d0 + 2)) & 1u);
            bv.w = (float)((w >> (d0 + 3)) & 1u);
            *(float4*)&Bt[ccb][(tid & 15) * 4] = bv;
        }
        __syncthreads();
        const int aBase = L0 - 31 * kc;
#pragma unroll
        for (int cc = 0; cc < 16; ++cc) {
            const float a0 = sbl[aBase - cc];
            const float a1 = sbl[aBase - cc + 1];
            const float a2 = sbl[aBase - cc + 2];
            const float a3 = sbl[aBase - cc + 3];
            const float4 bx = *(const float4*)&Bt[cc][tx * 4];
            acc[0][0] += a0 * bx.x; acc[0][1] += a0 * bx.y; acc[0][2] += a0 * bx.z; acc[0][3] += a0 * bx.w;
            acc[1][0] += a1 * bx.x; acc[1][1] += a1 * bx.y; acc[1][2] += a1 * bx.z; acc[1][3] += a1 * bx.w;
            acc[2][0] += a2 * bx.x; acc[2][1] += a2 * bx.y; acc[2][2] += a2 * bx.z; acc[2][3] += a2 * bx.w;
            acc[3][0] += a3 * bx.x; acc[3][1] += a3 * bx.y; acc[3][2] += a3 * bx.z; acc[3][3] += a3 * bx.w;
        }
        __syncthreads();
    }

    // store to partial plane tj, packed rows, layout [b][rowL][c], float4 over c
    float* plane = (tj == 0) ? p0 : (tj == 1) ? p1 : (tj == 2) ? p2 : p3;
    const int nrows = (4 - tj) * 256;
    const int bb = nb >> 5;
    const int c0 = h * 32 + d0;
#pragma unroll
    for (int r = 0; r < 4; ++r) {
        const int rowL = dt * 256 + iTile * 64 + ii0 + r;
        float4 st;
        st.x = acc[r][0]; st.y = acc[r][1]; st.z = acc[r][2]; st.w = acc[r][3];
        *(float4*)&plane[((size_t)bb * nrows + rowL) * 256 + c0] = st;
    }
}

// ---------------------------------------------------------------------------
// K4: combine S1 + bias partials, scale 0.125, LIF over t -> s2t
// ---------------------------------------------------------------------------
__global__ __launch_bounds__(256) void k4_lif2(
    const float* __restrict__ oatt,
    const float* __restrict__ p0, const float* __restrict__ p1,
    const float* __restrict__ p2, const float* __restrict__ p3,
    float* __restrict__ s2t)
{
    const int c = threadIdx.x;
    const int n = blockIdx.x;
    const int b = blockIdx.y;
    float memv = 0.0f, spk = 0.0f;
    for (int t = 0; t < T_; ++t) {
        const int l = t * N_ + n;
        float v = oatt[((size_t)b * TN_ + l) * C_ + c];
        v += p0[((size_t)b * 1024 + l) * 256 + c];
        if (t >= 1) v += p1[((size_t)b * 768 + (l - 256)) * 256 + c];
        if (t >= 2) v += p2[((size_t)b * 512 + (l - 512)) * 256 + c];
        if (t >= 3) v += p3[((size_t)b * 256 + (l - 768)) * 256 + c];
        const float m = (memv - 0.5f * spk) * 0.25f + 0.125f * v;
        memv = m;
        const float s = quant1f(m);
        s2t[((size_t)b * TN_ + l) * C_ + c] = s;
        spk = s;
    }
}

// ---------------------------------------------------------------------------
// K5: proj GEMM + bias + BN.
// ---------------------------------------------------------------------------
__global__ __launch_bounds__(256) void k5_proj_gemm(
    const float* __restrict__ s2t, const float* __restrict__ w,
    const float* __restrict__ bp,
    const float* __restrict__ gamma, const float* __restrict__ beta,
    const float* __restrict__ mean, const float* __restrict__ var,
    float* __restrict__ pbn)
{
    __shared__ float Wt[16][65];
    __shared__ float Xt[16][65];
    const int b = blockIdx.z;
    const int oBase = blockIdx.y * 64;
    const int lBase = blockIdx.x * 64;
    const int tid = threadIdx.x;
    const int ty = tid >> 4, tx = tid & 15;
    const float* xb = s2t + (size_t)b * TN_ * C_;

    float acc[4][4];
#pragma unroll
    for (int i = 0; i < 4; ++i)
#pragma unroll
        for (int j = 0; j < 4; ++j) acc[i][j] = 0.0f;

    for (int kc = 0; kc < 16; ++kc) {
        {
            const int cc = tid & 15, oo = tid >> 4;
#pragma unroll
            for (int r = 0; r < 4; ++r)
                Wt[cc][oo + 16 * r] = w[(size_t)(oBase + oo + 16 * r) * C_ + kc * 16 + cc];
        }
        {
            const int cc = tid & 15, ll0 = tid >> 4;
#pragma unroll
            for (int r = 0; r < 4; ++r)
                Xt[cc][ll0 + 16 * r] = xb[(size_t)(lBase + ll0 + 16 * r) * C_ + kc * 16 + cc];
        }
        __syncthreads();
#pragma unroll
        for (int cc = 0; cc < 16; ++cc) {
            float a[4], bx[4];
#pragma unroll
            for (int i = 0; i < 4; ++i) a[i] = Wt[cc][ty + 16 * i];
#pragma unroll
            for (int j = 0; j < 4; ++j) bx[j] = Xt[cc][tx + 16 * j];
#pragma unroll
            for (int i = 0; i < 4; ++i)
#pragma unroll
                for (int j = 0; j < 4; ++j) acc[i][j] += a[i] * bx[j];
        }
        __syncthreads();
    }

#pragma unroll
    for (int i = 0; i < 4; ++i) {
        const int o = oBase + ty + 16 * i;
        const float inv = 1.0f / sqrtf(var[o] + 1e-5f);
        const float g = gamma[o] * inv;
        const float mn = mean[o], bt = beta[o], bpo = bp[o];
#pragma unroll
        for (int j = 0; j < 4; ++j) {
            const int l = lBase + tx + 16 * j;
            pbn[((size_t)b * C_ + o) * TN_ + l] = ((acc[i][j] + bpo) - mn) * g + bt;
        }
    }
}

// ---------------------------------------------------------------------------
// K6: final LIF over t, write output [T][B][C][N]
// ---------------------------------------------------------------------------
__global__ __launch_bounds__(256) void k6_lif3(
    const float* __restrict__ pbn, float* __restrict__ out)
{
    const int n = threadIdx.x;
    const int c = blockIdx.x;
    const int b = blockIdx.y;
    const float* src = pbn + ((size_t)b * C_ + c) * TN_;
    float memv = 0.0f, spk = 0.0f;
    for (int t = 0; t < T_; ++t) {
        const float m = (memv - 0.5f * spk) * 0.25f + src[t * N_ + n];
        memv = m;
        const float s = quant1f(m);
        out[(((size_t)t * B_ + b) * C_ + c) * N_ + n] = s;
        spk = s;
    }
}

// ---------------------------------------------------------------------------
extern "C" void kernel_launch(void* const* d_in, const int* in_sizes, int n_in,
                              void* d_out, int out_size, void* d_ws, size_t ws_size,
                              hipStream_t stream)
{
    const float* x          = (const float*)d_in[0];
    const float* w_qkv      = (const float*)d_in[1];
    const float* qkv_gamma  = (const float*)d_in[2];
    const float* qkv_beta   = (const float*)d_in[3];
    const float* qkv_mean   = (const float*)d_in[4];
    const float* qkv_var    = (const float*)d_in[5];
    const float* bias_table = (const float*)d_in[6];
    const float* w_proj     = (const float*)d_in[7];
    const float* b_proj     = (const float*)d_in[8];
    const float* proj_gamma = (const float*)d_in[9];
    const float* proj_beta  = (const float*)d_in[10];
    const float* proj_mean  = (const float*)d_in[11];
    const float* proj_var   = (const float*)d_in[12];
    float* out = (float*)d_out;

    // workspace layout (bytes); region [0, 25165824) = qkv_bn, dead after K2,
    // then overlaid by ksel/vsel/Gf + the 4 packed bias-partial planes.
    char* ws = (char*)d_ws;
    float*    qkv_bn = (float*)(ws + 0);            // 25165824 B
    uint64_t* ksel   = (uint64_t*)(ws + 0);         //   262144 B (after K2)
    uint64_t* vsel   = (uint64_t*)(ws + 262144);    //   262144 B
    float*    Gf     = (float*)(ws + 524288);       //   262144 B
    float*    part0  = (float*)(ws + 1048576);      //  8388608 B (rows 0..1023)
    float*    part1  = (float*)(ws + 9437184);      //  6291456 B (rows 256..1023)
    float*    part2  = (float*)(ws + 15728640);     //  4194304 B (rows 512..1023)
    float*    part3  = (float*)(ws + 19922944);     //  2097152 B (rows 768..1023) end 22020096
    float*    oatt   = (float*)(ws + 25165824);     //  8388608 B (S1, unscaled)
    float*    s2t    = (float*)(ws + 33554432);     //  8388608 B
    float*    pbn    = (float*)(ws + 41943040);     //  8388608 B
    uint32_t* qbits  = (uint32_t*)(ws + 50331648);  //   262144 B
    uint32_t* kbits  = (uint32_t*)(ws + 50593792);
    uint32_t* vbits  = (uint32_t*)(ws + 50855936);
    float*    bcol   = (float*)(ws + 51118080);     //   217088 B, end 51335168

    k0_bcol<<<dim3((NH_ * BCOL_P_ + 255) / 256), 256, 0, stream>>>(bias_table, bcol);

    k1_qkv_gemm<<<dim3(16, 12, 8), 256, 0, stream>>>(
        x, w_qkv, qkv_gamma, qkv_beta, qkv_mean, qkv_var, qkv_bn);

    k2_lif_pack<<<dim3(24, 8), 256, 0, stream>>>(qkv_bn, qbits, kbits, vbits);

    k3_transpose<<<dim3(4, 8, 8), 256, 0, stream>>>(kbits, vbits, ksel, vsel);

    k3_gram<<<dim3(64), 256, 0, stream>>>(ksel, vsel, Gf);

    k3_s1<<<dim3(4, 8, 8), 256, 0, stream>>>(qbits, Gf, oatt);

    k3_bias_gemm<<<dim3(4, 4, 80), 256, 0, stream>>>(
        vbits, bcol, part0, part1, part2, part3);

    k4_lif2<<<dim3(256, 8), 256, 0, stream>>>(oatt, part0, part1, part2, part3, s2t);

    k5_proj_gemm<<<dim3(16, 4, 8), 256, 0, stream>>>(
        s2t, w_proj, b_proj, proj_gamma, proj_beta, proj_mean, proj_var, pbn);

    k6_lif3<<<dim3(256, 8), 256, 0, stream>>>(pbn, out);
}

// Round 4
// 244.719 us; speedup vs baseline: 2.8647x; 1.1111x over previous
//
#include <hip/hip_runtime.h>
#include <stdint.h>
#include <math.h>

// Problem constants
constexpr int T_ = 4;
constexpr int B_ = 8;
constexpr int C_ = 256;
constexpr int N_ = 256;          // H*W
constexpr int TN_ = 1024;        // T*N
constexpr int NH_ = 8;           // heads
constexpr int O3_ = 768;         // 3*C
constexpr int BIAS_ROWS_ = 6727; // 7*31*31
constexpr int BCOL_P_ = 6784;    // padded per-head bias column

__device__ __constant__ int TI_OF[10] = {0,1,1,2,2,2,3,3,3,3};
__device__ __constant__ int TJ_OF[10] = {0,0,1,0,1,2,0,1,2,3};

__device__ __forceinline__ float quant1f(float m) {
    return rintf(fminf(fmaxf(m, 0.0f), 1.0f));
}

// ---------------------------------------------------------------------------
// K0: compact bias_table column per head: bcol[h][r] = bias_table[r*8+h]
// ---------------------------------------------------------------------------
__global__ __launch_bounds__(256) void k0_bcol(
    const float* __restrict__ bias_table, float* __restrict__ bcol)
{
    const int idx = blockIdx.x * 256 + threadIdx.x;
    if (idx >= NH_ * BCOL_P_) return;
    const int h = idx / BCOL_P_, r = idx % BCOL_P_;
    bcol[idx] = (r < BIAS_ROWS_) ? bias_table[(size_t)r * NH_ + h] : 0.0f;
}

// ---------------------------------------------------------------------------
// K1: qkv = BN(w_qkv @ xf)   out[b][o][l]
// 96(M=o) x 128(N=l) tile, 256 threads, 12x4 microtile, K-chunk 16.
// Grid 8x8x8 = 512 blocks = exactly 2/CU. Ascending-k sum order (bit-identical
// to prior rounds). a/b LDS reads are float4 + broadcast, conflict-free.
// ---------------------------------------------------------------------------
__global__ __launch_bounds__(256) void k1_qkv_gemm(
    const float* __restrict__ x, const float* __restrict__ w,
    const float* __restrict__ gamma, const float* __restrict__ beta,
    const float* __restrict__ mean, const float* __restrict__ var,
    float* __restrict__ out)
{
    __shared__ float At[16][100];  // [k][m], m=96 (+4 pad)
    __shared__ float Bt[16][132];  // [k][n], n=128 (+4 pad)
    const int b = blockIdx.z;
    const int oBase = blockIdx.y * 96;
    const int lBase = blockIdx.x * 128;
    const int tid = threadIdx.x;
    const int tx = tid & 31;        // n: cols tx*4..tx*4+3
    const int ty = tid >> 5;        // m: rows {0,32,64}+ty*4..+3
    const float* xb = x + (size_t)b * C_ * TN_;

    float acc[12][4];
#pragma unroll
    for (int i = 0; i < 12; ++i)
#pragma unroll
        for (int j = 0; j < 4; ++j) acc[i][j] = 0.0f;

    const int b_kk = tid >> 4, b_c4 = (tid & 15) * 4;

    for (int kc = 0; kc < 16; ++kc) {
        const int k0 = kc * 16;
        // A: 96 rows x 16 k, as 768 float2 (3 per thread); store transposed
#pragma unroll
        for (int r = 0; r < 3; ++r) {
            const int q = tid + 256 * r;
            const int row = q >> 3, k2 = (q & 7) * 2;
            const float2 v = *(const float2*)&w[(size_t)(oBase + row) * C_ + k0 + k2];
            At[k2][row] = v.x;
            At[k2 + 1][row] = v.y;
        }
        // B: 16 k x 128 l, float4 coalesced
#pragma unroll
        for (int r = 0; r < 2; ++r) {
            const float4 v = *(const float4*)&xb[(size_t)(k0 + b_kk) * TN_ + lBase + b_c4 + 64 * r];
            *(float4*)&Bt[b_kk][b_c4 + 64 * r] = v;
        }
        __syncthreads();
#pragma unroll
        for (int cc = 0; cc < 16; ++cc) {
            float a[12], bb[4];
            *(float4*)&a[0] = *(const float4*)&At[cc][ty * 4];
            *(float4*)&a[4] = *(const float4*)&At[cc][32 + ty * 4];
            *(float4*)&a[8] = *(const float4*)&At[cc][64 + ty * 4];
            *(float4*)&bb[0] = *(const float4*)&Bt[cc][tx * 4];
#pragma unroll
            for (int i = 0; i < 12; ++i)
#pragma unroll
                for (int j = 0; j < 4; ++j) acc[i][j] += a[i] * bb[j];
        }
        __syncthreads();
    }

#pragma unroll
    for (int i = 0; i < 12; ++i) {
        const int o = oBase + (i >> 2) * 32 + ty * 4 + (i & 3);
        const float inv = 1.0f / sqrtf(var[o] + 1e-5f);
        const float g = gamma[o] * inv;
        const float mn = mean[o], bt = beta[o];
        float4 st;
        st.x = (acc[i][0] - mn) * g + bt;
        st.y = (acc[i][1] - mn) * g + bt;
        st.z = (acc[i][2] - mn) * g + bt;
        st.w = (acc[i][3] - mn) * g + bt;
        *(float4*)&out[((size_t)b * O3_ + o) * TN_ + lBase + tx * 4] = st;
    }
}

// ---------------------------------------------------------------------------
// K2: LIF over t on qkv_bn, pack 32 head-dims into one uint32 spike word.
// ---------------------------------------------------------------------------
__global__ __launch_bounds__(256) void k2_lif_pack(
    const float* __restrict__ qkv,
    uint32_t* __restrict__ qb, uint32_t* __restrict__ kb, uint32_t* __restrict__ vb)
{
    const int n = threadIdx.x;
    const int g = blockIdx.x;
    const int b = blockIdx.y;
    const int which = g >> 3, h = g & 7;
    uint32_t* dst = (which == 0) ? qb : (which == 1) ? kb : vb;
    const float* src = qkv + ((size_t)b * O3_ + g * 32) * TN_;

    float memv[32];
#pragma unroll
    for (int d = 0; d < 32; ++d) memv[d] = 0.0f;
    uint32_t prev = 0;

    for (int t = 0; t < T_; ++t) {
        uint32_t bits = 0;
#pragma unroll
        for (int d = 0; d < 32; ++d) {
            const float xv = src[(size_t)d * TN_ + t * N_ + n];
            const float m = (memv[d] - 0.5f * (float)((prev >> d) & 1u)) * 0.25f + xv;
            memv[d] = m;
            const float s = quant1f(m);
            bits |= ((uint32_t)s) << d;
        }
        prev = bits;
        dst[((size_t)b * NH_ + h) * TN_ + t * N_ + n] = bits;
    }
}

// ---------------------------------------------------------------------------
// K3t: ballot bit-transpose of k and v spikes into per-(b,h,t) column masks.
// ---------------------------------------------------------------------------
__global__ __launch_bounds__(256) void k3_transpose(
    const uint32_t* __restrict__ kb, const uint32_t* __restrict__ vb,
    uint64_t* __restrict__ ksel, uint64_t* __restrict__ vsel)
{
    const int t = blockIdx.x;
    const int h = blockIdx.y;
    const int b = blockIdx.z;
    const int bh = b * NH_ + h;
    const int tid = threadIdx.x;
    const int q = tid >> 6, lane = tid & 63;
    const int j = t * N_ + q * 64 + lane;

    const uint32_t kw = kb[(size_t)bh * TN_ + j];
    const uint32_t vw = vb[(size_t)bh * TN_ + j];
#pragma unroll
    for (int d = 0; d < 32; ++d) {
        const uint64_t mk = __ballot((kw >> d) & 1u);
        const uint64_t mv = __ballot((vw >> d) & 1u);
        if (lane == 0) {
            ksel[((size_t)(bh * 4 + t) * 32 + d) * 4 + q] = mk;
            vsel[((size_t)(bh * 4 + t) * 32 + d) * 4 + q] = mv;
        }
    }
}

// ---------------------------------------------------------------------------
// K3g: G_t[d2][d] = sum_{j < (t+1)*256} k[j,d2]*v[j,d]  (cumulative over t)
// ---------------------------------------------------------------------------
__global__ __launch_bounds__(256) void k3_gram(
    const uint64_t* __restrict__ ksel, const uint64_t* __restrict__ vsel,
    float* __restrict__ Gf)
{
    const int bh = blockIdx.x;
    const int tid = threadIdx.x;
    const int d = tid & 31;
#pragma unroll
    for (int s = 0; s < 4; ++s) {
        const int d2 = (tid >> 5) + 8 * s;
        int cum = 0;
#pragma unroll
        for (int t = 0; t < T_; ++t) {
            const uint64_t* kp = ksel + ((size_t)(bh * 4 + t) * 32 + d2) * 4;
            const uint64_t* vp = vsel + ((size_t)(bh * 4 + t) * 32 + d) * 4;
            int p = 0;
#pragma unroll
            for (int w = 0; w < 4; ++w) p += __popcll(kp[w] & vp[w]);
            cum += p;
            Gf[(size_t)(bh * 4 + t) * 1024 + d2 * 32 + d] = (float)cum;
        }
    }
}

// ---------------------------------------------------------------------------
// K3s1: S1[i,d] = sum_{d2} qbit[i,d2] * G_ti[d2,d]  -> oatt (unscaled)
// ---------------------------------------------------------------------------
__global__ __launch_bounds__(256) void k3_s1(
    const uint32_t* __restrict__ qb, const float* __restrict__ Gf,
    float* __restrict__ oatt)
{
    __shared__ float sG[1024];
    const int ti = blockIdx.x;
    const int h = blockIdx.y;
    const int b = blockIdx.z;
    const int bh = b * NH_ + h;
    const int tid = threadIdx.x;
    const int d = tid & 31;

    for (int idx = tid; idx < 1024; idx += 256)
        sG[idx] = Gf[(size_t)(bh * 4 + ti) * 1024 + idx];
    __syncthreads();

    const uint32_t* qbh = qb + (size_t)bh * TN_;
    for (int step = 0; step < 32; ++step) {
        const int i = ti * N_ + step * 8 + (tid >> 5);
        const uint32_t q = qbh[i];
        float acc = 0.0f;
#pragma unroll
        for (int d2 = 0; d2 < 32; ++d2)
            acc += ((q >> d2) & 1u) ? sG[d2 * 32 + d] : 0.0f;
        oatt[((size_t)b * TN_ + i) * C_ + h * 32 + d] = acc;
    }
}

// ---------------------------------------------------------------------------
// K3gemm: balanced split-K bias GEMM (unchanged from R3).
// ---------------------------------------------------------------------------
__global__ __launch_bounds__(256) void k3_bias_gemm(
    const uint32_t* __restrict__ vb, const float* __restrict__ bcol,
    float* __restrict__ p0, float* __restrict__ p1,
    float* __restrict__ p2, float* __restrict__ p3)
{
    __shared__ float sbl[640];
    __shared__ float Bt[16][64];

    const int z = blockIdx.z;            // 0..79
    const int h = z / 10;
    const int p = z % 10;
    const int ti = TI_OF[p], tj = TJ_OF[p];
    const int dt = ti - tj;
    const int iTile = blockIdx.y;        // 0..3
    const int nBase = blockIdx.x * 64;   // 0..3
    const int tid = threadIdx.x;

    const int base = 3363 + 961 * dt + 124 * iTile - 480;
    const float* bch = bcol + h * BCOL_P_;
    for (int s = tid; s < 640; s += 256) sbl[s] = bch[base + s];

    const int ty = tid >> 4, tx = tid & 15;
    const int ii0 = ty * 4;
    const int hi = (iTile * 64 + ii0) >> 4;
    const int wi0 = ii0 & 15;
    const int L0 = 31 * hi + wi0 - 124 * iTile + 480;

    const int ccb = tid >> 4;
    const int nb = nBase + (tid & 15) * 4;
    const int d0 = nb & 31;
    const uint32_t* vbw = vb + (((size_t)(nb >> 5)) * NH_ + h) * TN_ + tj * 256 + ccb;

    float acc[4][4];
#pragma unroll
    for (int i = 0; i < 4; ++i)
#pragma unroll
        for (int j = 0; j < 4; ++j) acc[i][j] = 0.0f;

    __syncthreads();

    for (int kc = 0; kc < 16; ++kc) {
        {
            const uint32_t w = vbw[kc * 16];
            float4 bv;
            bv.x = (float)((w >> d0) & 1u);
            bv.y = (float)((w >> (d0 + 1)) & 1u);
            bv.z = (float)((w >> (d0 + 2)) & 1u);
            bv.w = (float)((w >> (d0 + 3)) & 1u);
            *(float4*)&Bt[ccb][(tid & 15) * 4] = bv;
        }
        __syncthreads();
        const int aBase = L0 - 31 * kc;
#pragma unroll
        for (int cc = 0; cc < 16; ++cc) {
            const float a0 = sbl[aBase - cc];
            const float a1 = sbl[aBase - cc + 1];
            const float a2 = sbl[aBase - cc + 2];
            const float a3 = sbl[aBase - cc + 3];
            const float4 bx = *(const float4*)&Bt[cc][tx * 4];
            acc[0][0] += a0 * bx.x; acc[0][1] += a0 * bx.y; acc[0][2] += a0 * bx.z; acc[0][3] += a0 * bx.w;
            acc[1][0] += a1 * bx.x; acc[1][1] += a1 * bx.y; acc[1][2] += a1 * bx.z; acc[1][3] += a1 * bx.w;
            acc[2][0] += a2 * bx.x; acc[2][1] += a2 * bx.y; acc[2][2] += a2 * bx.z; acc[2][3] += a2 * bx.w;
            acc[3][0] += a3 * bx.x; acc[3][1] += a3 * bx.y; acc[3][2] += a3 * bx.z; acc[3][3] += a3 * bx.w;
        }
        __syncthreads();
    }

    float* plane = (tj == 0) ? p0 : (tj == 1) ? p1 : (tj == 2) ? p2 : p3;
    const int nrows = (4 - tj) * 256;
    const int bb = nb >> 5;
    const int c0 = h * 32 + d0;
#pragma unroll
    for (int r = 0; r < 4; ++r) {
        const int rowL = dt * 256 + iTile * 64 + ii0 + r;
        float4 st;
        st.x = acc[r][0]; st.y = acc[r][1]; st.z = acc[r][2]; st.w = acc[r][3];
        *(float4*)&plane[((size_t)bb * nrows + rowL) * 256 + c0] = st;
    }
}

// ---------------------------------------------------------------------------
// K4: combine S1 + bias partials, scale 0.125, LIF over t -> bit-packed spikes
// s2c[(b*1024+l)*8 + (c>>5)] bit (c&31) = spike. Packed via __ballot.
// ---------------------------------------------------------------------------
__global__ __launch_bounds__(256) void k4_lif2(
    const float* __restrict__ oatt,
    const float* __restrict__ p0, const float* __restrict__ p1,
    const float* __restrict__ p2, const float* __restrict__ p3,
    uint32_t* __restrict__ s2c)
{
    const int c = threadIdx.x;
    const int n = blockIdx.x;
    const int b = blockIdx.y;
    const int lane = c & 63;
    float memv = 0.0f, spk = 0.0f;
    for (int t = 0; t < T_; ++t) {
        const int l = t * N_ + n;
        float v = oatt[((size_t)b * TN_ + l) * C_ + c];
        v += p0[((size_t)b * 1024 + l) * 256 + c];
        if (t >= 1) v += p1[((size_t)b * 768 + (l - 256)) * 256 + c];
        if (t >= 2) v += p2[((size_t)b * 512 + (l - 512)) * 256 + c];
        if (t >= 3) v += p3[((size_t)b * 256 + (l - 768)) * 256 + c];
        const float m = (memv - 0.5f * spk) * 0.25f + 0.125f * v;
        memv = m;
        const float s = quant1f(m);
        spk = s;
        const uint64_t mask = __ballot(s != 0.0f);
        if (lane == 0)
            s2c[((size_t)b * TN_ + l) * 8 + (c >> 5)] = (uint32_t)mask;
        else if (lane == 32)
            s2c[((size_t)b * TN_ + l) * 8 + (c >> 5)] = (uint32_t)(mask >> 32);
    }
}

// ---------------------------------------------------------------------------
// K5: proj GEMM + bias + BN, B operand expanded from bit-packed spikes.
// 32(M=o) x 128(N=l) tile, 256 threads, 4x4 microtile, K-chunk 16.
// Grid 8x8x8 = 512 blocks. Ascending-k order == prior rounds (exact).
// ---------------------------------------------------------------------------
__global__ __launch_bounds__(256) void k5_proj_gemm(
    const uint32_t* __restrict__ s2c, const float* __restrict__ w,
    const float* __restrict__ bp,
    const float* __restrict__ gamma, const float* __restrict__ beta,
    const float* __restrict__ mean, const float* __restrict__ var,
    float* __restrict__ pbn)
{
    __shared__ float At[16][36];   // [k][m], m=32 (+4 pad)
    __shared__ float Bt[16][132];  // [k][n], n=128 (+4 pad)
    const int b = blockIdx.z;
    const int oBase = blockIdx.y * 32;
    const int lBase = blockIdx.x * 128;
    const int tid = threadIdx.x;
    const int tx = tid & 31;       // n: cols tx*4..+3
    const int ty = tid >> 5;       // m: rows ty*4..+3

    const int a_row = tid >> 3, a_k2 = (tid & 7) * 2;
    const int b_ll = tid >> 1, b_sub = tid & 1;
    const uint32_t* srow = s2c + ((size_t)b * TN_ + lBase + b_ll) * 8;

    float acc[4][4];
#pragma unroll
    for (int i = 0; i < 4; ++i)
#pragma unroll
        for (int j = 0; j < 4; ++j) acc[i][j] = 0.0f;

    for (int kc = 0; kc < 16; ++kc) {
        const int k0 = kc * 16;
        {
            const float2 v = *(const float2*)&w[(size_t)(oBase + a_row) * C_ + k0 + a_k2];
            At[a_k2][a_row] = v.x;
            At[a_k2 + 1][a_row] = v.y;
        }
        {
            const uint32_t wd = srow[kc >> 1];
            const int sh = ((kc & 1) << 4) + (b_sub << 3);
#pragma unroll
            for (int u = 0; u < 8; ++u)
                Bt[(b_sub << 3) + u][b_ll] = (float)((wd >> (sh + u)) & 1u);
        }
        __syncthreads();
#pragma unroll
        for (int cc = 0; cc < 16; ++cc) {
            float a[4], bb[4];
            *(float4*)&a[0] = *(const float4*)&At[cc][ty * 4];
            *(float4*)&bb[0] = *(const float4*)&Bt[cc][tx * 4];
#pragma unroll
            for (int i = 0; i < 4; ++i)
#pragma unroll
                for (int j = 0; j < 4; ++j) acc[i][j] += a[i] * bb[j];
        }
        __syncthreads();
    }

#pragma unroll
    for (int i = 0; i < 4; ++i) {
        const int o = oBase + ty * 4 + i;
        const float inv = 1.0f / sqrtf(var[o] + 1e-5f);
        const float g = gamma[o] * inv;
        const float mn = mean[o], bt = beta[o], bpo = bp[o];
        float4 st;
        st.x = ((acc[i][0] + bpo) - mn) * g + bt;
        st.y = ((acc[i][1] + bpo) - mn) * g + bt;
        st.z = ((acc[i][2] + bpo) - mn) * g + bt;
        st.w = ((acc[i][3] + bpo) - mn) * g + bt;
        *(float4*)&pbn[((size_t)b * C_ + o) * TN_ + lBase + tx * 4] = st;
    }
}

// ---------------------------------------------------------------------------
// K6: final LIF over t, write output [T][B][C][N]
// ---------------------------------------------------------------------------
__global__ __launch_bounds__(256) void k6_lif3(
    const float* __restrict__ pbn, float* __restrict__ out)
{
    const int n = threadIdx.x;
    const int c = blockIdx.x;
    const int b = blockIdx.y;
    const float* src = pbn + ((size_t)b * C_ + c) * TN_;
    float memv = 0.0f, spk = 0.0f;
    for (int t = 0; t < T_; ++t) {
        const float m = (memv - 0.5f * spk) * 0.25f + src[t * N_ + n];
        memv = m;
        const float s = quant1f(m);
        out[(((size_t)t * B_ + b) * C_ + c) * N_ + n] = s;
        spk = s;
    }
}

// ---------------------------------------------------------------------------
extern "C" void kernel_launch(void* const* d_in, const int* in_sizes, int n_in,
                              void* d_out, int out_size, void* d_ws, size_t ws_size,
                              hipStream_t stream)
{
    const float* x          = (const float*)d_in[0];
    const float* w_qkv      = (const float*)d_in[1];
    const float* qkv_gamma  = (const float*)d_in[2];
    const float* qkv_beta   = (const float*)d_in[3];
    const float* qkv_mean   = (const float*)d_in[4];
    const float* qkv_var    = (const float*)d_in[5];
    const float* bias_table = (const float*)d_in[6];
    const float* w_proj     = (const float*)d_in[7];
    const float* b_proj     = (const float*)d_in[8];
    const float* proj_gamma = (const float*)d_in[9];
    const float* proj_beta  = (const float*)d_in[10];
    const float* proj_mean  = (const float*)d_in[11];
    const float* proj_var   = (const float*)d_in[12];
    float* out = (float*)d_out;

    // workspace layout (bytes)
    char* ws = (char*)d_ws;
    float*    qkv_bn = (float*)(ws + 0);            // 25165824 B (dead after K2)
    uint64_t* ksel   = (uint64_t*)(ws + 0);         //   262144 B (after K2)
    uint64_t* vsel   = (uint64_t*)(ws + 262144);    //   262144 B
    float*    Gf     = (float*)(ws + 524288);       //   262144 B
    float*    part0  = (float*)(ws + 1048576);      //  8388608 B
    float*    part1  = (float*)(ws + 9437184);      //  6291456 B
    float*    part2  = (float*)(ws + 15728640);     //  4194304 B
    float*    part3  = (float*)(ws + 19922944);     //  2097152 B
    float*    oatt   = (float*)(ws + 25165824);     //  8388608 B (S1, unscaled)
    uint32_t* s2c    = (uint32_t*)(ws + 33554432);  //   262144 B (packed spikes)
    float*    pbn    = (float*)(ws + 41943040);     //  8388608 B
    uint32_t* qbits  = (uint32_t*)(ws + 50331648);  //   262144 B
    uint32_t* kbits  = (uint32_t*)(ws + 50593792);
    uint32_t* vbits  = (uint32_t*)(ws + 50855936);
    float*    bcol   = (float*)(ws + 51118080);     //   217088 B, end 51335168

    k0_bcol<<<dim3((NH_ * BCOL_P_ + 255) / 256), 256, 0, stream>>>(bias_table, bcol);

    k1_qkv_gemm<<<dim3(8, 8, 8), 256, 0, stream>>>(
        x, w_qkv, qkv_gamma, qkv_beta, qkv_mean, qkv_var, qkv_bn);

    k2_lif_pack<<<dim3(24, 8), 256, 0, stream>>>(qkv_bn, qbits, kbits, vbits);

    k3_transpose<<<dim3(4, 8, 8), 256, 0, stream>>>(kbits, vbits, ksel, vsel);

    k3_gram<<<dim3(64), 256, 0, stream>>>(ksel, vsel, Gf);

    k3_s1<<<dim3(4, 8, 8), 256, 0, stream>>>(qbits, Gf, oatt);

    k3_bias_gemm<<<dim3(4, 4, 80), 256, 0, stream>>>(
        vbits, bcol, part0, part1, part2, part3);

    k4_lif2<<<dim3(256, 8), 256, 0, stream>>>(oatt, part0, part1, part2, part3, s2c);

    k5_proj_gemm<<<dim3(8, 8, 8), 256, 0, stream>>>(
        s2c, w_proj, b_proj, proj_gamma, proj_beta, proj_mean, proj_var, pbn);

    k6_lif3<<<dim3(256, 8), 256, 0, stream>>>(pbn, out);
}